// Round 11
// baseline (40.229 us; speedup 1.0000x reference)
//
#include <hip/hip_runtime.h>
#include <hip/hip_bf16.h>

#define MM 64
#define KTOT 4096
#define NN 11008
#define PACKS 1376    // NN / 8
#define BN 128
#define NBLK 86       // NN / BN
#define KSPLIT 8
#define BKCHUNK 512   // KTOT / KSPLIT
#define BK 64         // k per step
#define NBLOCKS (NBLK * KSPLIT)  // 688

typedef float f32x4 __attribute__((ext_vector_type(4)));
typedef short bf16x8 __attribute__((ext_vector_type(8)));

__device__ __forceinline__ unsigned int f2bf(float f) {
    unsigned int b = __float_as_uint(f);
    return (b + 0x7FFFu + ((b >> 16) & 1u)) >> 16;   // RNE to bf16
}
__device__ __forceinline__ float bf2f(unsigned int h) {
    return __uint_as_float(h << 16);
}

// out = bias broadcast over rows (atomic targets accumulate on top)
__global__ __launch_bounds__(256) void init_out(const float* __restrict__ bias,
                                                float* __restrict__ out) {
    const int t = blockIdx.x * 256 + threadIdx.x;   // 688*256 float4s
    const int n = (t * 4) % NN;
    *reinterpret_cast<float4*>(reinterpret_cast<float*>(out) + t * 4) =
        *reinterpret_cast<const float4*>(bias + n);
}

// Fully fused AWQ GEMM: inline x f32->bf16 staging (+ in-block group row-sums),
// rolled K-loop (4 it x 2 phases), bias-trick B-build from transposed packed qt,
// group correction ACC += s*P - s*(128+z)*R, atomic epilogue into bias-filled out.
__global__ __launch_bounds__(512, 4) void awq_mfma(
    const float* __restrict__ x, const int* __restrict__ qw,
    const int* __restrict__ qz, const float* __restrict__ sc,
    float* __restrict__ out)
{
    __shared__ __attribute__((aligned(16))) unsigned int qt[2][16][68];  // [cp][k], pad
    __shared__ __attribute__((aligned(16))) unsigned int xst[2][64][32]; // [m][k-dw swz]
    __shared__ __attribute__((aligned(16))) float Rloc[64];              // group row sums

    const int tid = threadIdx.x, wv = tid >> 6, l = tid & 63;
    const int bid = blockIdx.x;
    const int ks  = bid & 7;              // k-stripe == XCD (round-robin dispatch)
    const int bn  = bid >> 3;
    const int k00 = ks * BKCHUNK;
    const int l15 = l & 15, l4 = l >> 4;

    // block-cooperative staging maps (fully coalesced)
    const int qrow = tid >> 3, qc2 = (tid & 7) * 2;   // 64 k-rows x 16 dw (64B/row)
    const int xrow = tid >> 3, xsl = tid & 7;         // 64 m-rows x 8 slots (32B f32)

    // compute-lane constants
    const int nloc = wv * 16 + l15;
    const int cp   = nloc >> 3;
    const int j    = nloc & 7;
    const int sh   = ((j >> 1) << 2) + ((j & 1) << 4);// AWQ nibble shift (validated)
    const int ncol = bn * BN + nloc;

    const int qstride = BK * PACKS;
    const int* qp = qw + (k00 + qrow) * PACKS + bn * 16 + qc2;
    const float* xp = x + xrow * KTOT + k00 + xsl * 8;
    const int g0 = k00 >> 7;

    uint2 qreg0, qreg1;
    float4 xr0a, xr0b, xr1a, xr1b;
    float s_c, szb_c, s_n = 0.f;
    int zz_n = 0;
    float rs = 0.f;
    f32x4 accP[4], ACC[4] = {};

    // prologue
    qreg0 = *reinterpret_cast<const uint2*>(qp);
    xr0a  = *reinterpret_cast<const float4*>(xp);
    xr0b  = *reinterpret_cast<const float4*>(xp + 4);
    s_c = sc[g0 * NN + ncol];
    {
        const int zz = qz[g0 * PACKS + (ncol >> 3)];
        szb_c = s_c * (128.0f + (float)((zz >> sh) & 0xF));
    }

#define COMPUTE(B) do {                                                       \
    _Pragma("unroll")                                                         \
    for (int kk = 0; kk < 2; ++kk) {                                          \
        const int k0 = kk * 32 + l4 * 8;                                      \
        const uint4 qa = *reinterpret_cast<const uint4*>(&qt[B][cp][k0]);     \
        const uint4 qb = *reinterpret_cast<const uint4*>(&qt[B][cp][k0 + 4]); \
        uint4 db;                                                             \
        db.x = (((qa.x >> sh) & 0xFu) | (((qa.y >> sh) & 0xFu) << 16)) | 0x43004300u; \
        db.y = (((qa.z >> sh) & 0xFu) | (((qa.w >> sh) & 0xFu) << 16)) | 0x43004300u; \
        db.z = (((qb.x >> sh) & 0xFu) | (((qb.y >> sh) & 0xFu) << 16)) | 0x43004300u; \
        db.w = (((qb.z >> sh) & 0xFu) | (((qb.w >> sh) & 0xFu) << 16)) | 0x43004300u; \
        const bf16x8 bfr = __builtin_bit_cast(bf16x8, db);                    \
        _Pragma("unroll")                                                     \
        for (int mt = 0; mt < 4; ++mt) {                                      \
            const int r = mt * 16 + l15;                                      \
            const int c = (kk * 16 + l4 * 4) ^ ((r & 7) << 2);                \
            const bf16x8 af = *reinterpret_cast<const bf16x8*>(&xst[B][r][c]);\
            accP[mt] = __builtin_amdgcn_mfma_f32_16x16x32_bf16(af, bfr, accP[mt], 0, 0, 0); \
        }                                                                     \
    }                                                                         \
} while (0)

// convert 8 staged f32 to packed bf16 + accumulate this thread's row partial
#define CVT_STAGE(B, VA, VB) do {                                             \
    const unsigned a0 = f2bf(VA.x), a1 = f2bf(VA.y), a2 = f2bf(VA.z), a3 = f2bf(VA.w); \
    const unsigned b0 = f2bf(VB.x), b1 = f2bf(VB.y), b2 = f2bf(VB.z), b3 = f2bf(VB.w); \
    rs += bf2f(a0) + bf2f(a1) + bf2f(a2) + bf2f(a3)                            \
        + bf2f(b0) + bf2f(b1) + bf2f(b2) + bf2f(b3);                           \
    const uint4 xv = make_uint4(a0 | (a1 << 16), a2 | (a3 << 16),              \
                                b0 | (b1 << 16), b2 | (b3 << 16));             \
    *reinterpret_cast<uint4*>(&xst[B][xrow][(xsl ^ (xrow & 7)) << 2]) = xv;    \
} while (0)

#pragma clang loop unroll(disable)
    for (int it = 0; it < 4; ++it) {
        // ======== phase 0 (even step, buffer 0) ========
        qreg1 = *reinterpret_cast<const uint2*>(qp + qstride);     // in-bounds always
        xr1a  = *reinterpret_cast<const float4*>(xp + BK);
        xr1b  = *reinterpret_cast<const float4*>(xp + BK + 4);
        accP[0] = (f32x4){};
        accP[1] = (f32x4){};
        accP[2] = (f32x4){};
        accP[3] = (f32x4){};
        if (it < 3) {   // next group's scale/zero
            s_n  = sc[(g0 + it + 1) * NN + ncol];
            zz_n = qz[(g0 + it + 1) * PACKS + (ncol >> 3)];
        }
        qt[0][qc2][qrow]     = qreg0.x;
        qt[0][qc2 + 1][qrow] = qreg0.y;
        rs = 0.f;
        CVT_STAGE(0, xr0a, xr0b);
        asm volatile("s_waitcnt lgkmcnt(0)\n\ts_barrier" ::: "memory");
        COMPUTE(0);

        // ======== phase 1 (odd step, buffer 1) ========
        if (it < 3) {   // prefetch next even step (guarded: OOB at it=3)
            qreg0 = *reinterpret_cast<const uint2*>(qp + 2 * qstride);
            xr0a  = *reinterpret_cast<const float4*>(xp + 2 * BK);
            xr0b  = *reinterpret_cast<const float4*>(xp + 2 * BK + 4);
        }
        qt[1][qc2][qrow]     = qreg1.x;
        qt[1][qc2 + 1][qrow] = qreg1.y;
        CVT_STAGE(1, xr1a, xr1b);
        // finish this group's row sums: 8 lanes (xsl 0..7) hold partials of one row
        rs += __shfl_xor(rs, 1);
        rs += __shfl_xor(rs, 2);
        rs += __shfl_xor(rs, 4);
        if (xsl == 0) Rloc[xrow] = rs;
        asm volatile("s_waitcnt lgkmcnt(0)\n\ts_barrier" ::: "memory");
        COMPUTE(1);

        // ---- group end: ACC += s*P - s*(128+z)*R (R from block-local Rloc) ----
#pragma unroll
        for (int mt = 0; mt < 4; ++mt) {
            const float4 r4 = *reinterpret_cast<const float4*>(&Rloc[mt * 16 + l4 * 4]);
            const float rr[4] = { r4.x, r4.y, r4.z, r4.w };
#pragma unroll
            for (int r = 0; r < 4; ++r) {
                ACC[mt][r] = fmaf(s_c, accP[mt][r], ACC[mt][r]);
                ACC[mt][r] = fmaf(-szb_c, rr[r], ACC[mt][r]);
            }
        }
        s_c   = s_n;    // stale at it=3, unused
        szb_c = s_n * (128.0f + (float)((zz_n >> sh) & 0xF));

        qp += 2 * qstride;
        xp += 2 * BK;
    }
#undef COMPUTE
#undef CVT_STAGE

    // ---- epilogue: atomic accumulate into bias-filled out ----
    float* pout = out + bn * BN + wv * 16 + l15;
#pragma unroll
    for (int mt = 0; mt < 4; ++mt) {
        const int r0 = mt * 16 + l4 * 4;
#pragma unroll
        for (int r = 0; r < 4; ++r)
            atomicAdd(&pout[(r0 + r) * NN], ACC[mt][r]);
    }
}

extern "C" void kernel_launch(void* const* d_in, const int* in_sizes, int n_in,
                              void* d_out, int out_size, void* d_ws, size_t ws_size,
                              hipStream_t stream) {
    const float* x    = (const float*)d_in[0];
    const int*   qw   = (const int*)d_in[1];
    const int*   qz   = (const int*)d_in[2];
    const float* sc   = (const float*)d_in[3];
    const float* bias = (const float*)d_in[4];
    float* out = (float*)d_out;

    init_out<<<dim3(MM * NN / 4 / 256), 256, 0, stream>>>(bias, out);
    awq_mfma<<<dim3(NBLOCKS), 512, 0, stream>>>(x, qw, qz, sc, out);
}